// Round 3
// baseline (108.835 us; speedup 1.0000x reference)
//
#include <hip/hip_runtime.h>
#include <math.h>

#define DD 8
#define MM 7
#define MOO 9
#define NPTS 100
#define EPSF 1e-5f

#define THREADS 512
#define ITERS 16          // THREADS*4*ITERS == 32768 rules
#define CAP 512           // candidate buffer capacity

// ---------------- pack kernel: antecedents -> packed byte-offset word -------
// w = ((code & 4095) << 2) | (((code >> 12) & 4095) << 2) << 16
//   lo 16 bits: byte offset into quad table 0 (dims 0-3)
//   hi 16 bits: byte offset into quad table 1 (dims 4-7)
__global__ __launch_bounds__(256) void pack_kernel(const int* __restrict__ ant,
                                                   unsigned* __restrict__ g_off,
                                                   int R) {
    int r = blockIdx.x * 256 + threadIdx.x;
    if (r < R) {
        const int4* a = reinterpret_cast<const int4*>(ant) + (size_t)r * 2;
        int4 lo = a[0], hi = a[1];
        int v[8] = {lo.x, lo.y, lo.z, lo.w, hi.x, hi.y, hi.z, hi.w};
        unsigned code = 0u;
        #pragma unroll
        for (int i = 0; i < 8; ++i) {
            int c = v[i];
            c = (c < 0) ? 7 : (c > MM - 1 ? MM - 1 : c);   // -1 -> wildcard slot 7
            code |= (unsigned)c << (3 * i);
        }
        g_off[r] = ((code & 4095u) << 2) | ((code >> 12) << 18);
    }
}

// ---------------- sort kernel: bucket by hi-12 bits, wave-friendly scatter --
// Single block. After this, at each wave-instruction of the main kernel the 64
// lanes read 64 CONSECUTIVE sorted rules -> hi-table reads are runs of ~8
// equal words (broadcast, ~conflict-free). Order within a bucket is arbitrary
// (atomic scatter) -- harmless: threshold proof and final exact selection are
// independent of rule->thread assignment.
__global__ __launch_bounds__(1024) void sort_kernel(const unsigned* __restrict__ g_off,
                                                    unsigned* __restrict__ g_soff,
                                                    int* __restrict__ g_sidx,
                                                    int R) {
    __shared__ unsigned hist[4096];
    __shared__ unsigned aux[1024];
    const int tid = threadIdx.x;

    for (int i = tid; i < 4096; i += 1024) hist[i] = 0u;
    __syncthreads();

    for (int r = tid; r < R; r += 1024)
        atomicAdd(&hist[g_off[r] >> 18], 1u);
    __syncthreads();

    // exclusive prefix sum over 4096 buckets (4 per thread + block scan)
    unsigned h0 = hist[4 * tid], h1 = hist[4 * tid + 1];
    unsigned h2 = hist[4 * tid + 2], h3 = hist[4 * tid + 3];
    aux[tid] = h0 + h1 + h2 + h3;
    __syncthreads();
    for (int off = 1; off < 1024; off <<= 1) {
        unsigned v = (tid >= off) ? aux[tid - off] : 0u;
        __syncthreads();
        aux[tid] += v;
        __syncthreads();
    }
    unsigned base = tid ? aux[tid - 1] : 0u;
    hist[4 * tid]     = base;
    hist[4 * tid + 1] = base + h0;
    hist[4 * tid + 2] = base + h0 + h1;
    hist[4 * tid + 3] = base + h0 + h1 + h2;
    __syncthreads();

    // scatter with the lane/slot permutation:
    // main kernel reads flat position 4*(j*512+t)+s; we want rank q to land so
    // that lanes of one wave-instruction see consecutive q.
    for (int r = tid; r < R; r += 1024) {
        unsigned w = g_off[r];
        unsigned q = atomicAdd(&hist[w >> 18], 1u);
        unsigned p = (q & ~255u) | ((q & 63u) << 2) | ((q >> 6) & 3u);
        g_soff[p] = w;
        g_sidx[p] = r;
    }
}

// ---------------- fast kernel: one block (512 thr) per batch row ------------
template <bool SORTED>
__global__ __launch_bounds__(THREADS, 6) void anfis_fast(
    const float* __restrict__ x,
    const unsigned* __restrict__ stream_off,   // sorted (or raw) offset words
    const int* __restrict__ g_sidx,            // rank -> original rule (SORTED)
    const int* __restrict__ consequents,
    const float* __restrict__ in_centers,   // [D][M]
    const float* __restrict__ in_widths,    // [D][M]
    const float* __restrict__ out_centers,  // [MO]
    const float* __restrict__ out_widths,   // [MO]
    float* __restrict__ out)
{
    __shared__ float mu[64];          // [d][c], c==7 -> 1.0
    __shared__ float pairs[256];      // 4 x 64 pair products
    __shared__ float quads[8192];     // 2 x 4096 quad products (byte-indexed)
    __shared__ float s0s[MOO], s1s[MOO];
    __shared__ float smax[THREADS];
    __shared__ float sthr;
    __shared__ int   scnt;
    __shared__ float cvals[CAP];
    __shared__ int   cidx[CAP];
    __shared__ float wv[8];
    __shared__ int   wc[8];

    const int tid = threadIdx.x;
    const int b   = blockIdx.x;

    // --- phase 0: membership table + defuzz constants ---
    if (tid < 64) {
        int d = tid >> 3, c = tid & 7;
        float v = 1.0f;
        if (c < MM) {
            float z = (x[b * DD + d] - in_centers[d * MM + c]) / in_widths[d * MM + c];
            v = expf(-0.5f * z * z);
            v = fminf(v, 1.0f);
            v = fmaxf(v, EPSF);
        }
        mu[tid] = v;
    } else if (tid < 64 + MOO) {
        int mo = tid - 64;
        float oc = out_centers[mo], ow = out_widths[mo];
        float s0 = 0.0f, s1 = 0.0f;
        for (int p = 0; p < NPTS; ++p) {
            float u = (float)p * (1.0f / 99.0f);
            float z = (u - oc) / ow;
            float e = expf(-0.5f * z * z);
            s0 += e;
            s1 += u * e;
        }
        s0s[mo] = s0;
        s1s[mo] = s1;
    }
    __syncthreads();

    // --- phase 1: pair products (4 tables x 64) ---
    if (tid < 256) {
        int p = tid >> 6, q = tid & 63;
        pairs[tid] = mu[(2 * p) * 8 + (q & 7)] * mu[(2 * p + 1) * 8 + (q >> 3)];
    }
    __syncthreads();

    // --- phase 2: quad products (2 tables x 4096) ---
    #pragma unroll
    for (int k = tid; k < 8192; k += THREADS) {
        int t = k & 4095, hi = k >> 12;      // hi in {0,1}
        quads[k] = pairs[hi * 128 + (t & 63)] * pairs[hi * 128 + 64 + ((t >> 6) & 63)];
    }
    if (tid == 0) scnt = 0;
    __syncthreads();

    // --- phase 3: evaluate all rules, track per-thread max only ---
    const uint4* pk4 = reinterpret_cast<const uint4*>(stream_off);
    const char* qb = (const char*)quads;
    float mymax = -1.0f;
    uint4 cur = pk4[tid];
    #pragma unroll
    for (int j = 0; j < ITERS; ++j) {
        uint4 nxt;
        if (j + 1 < ITERS) nxt = pk4[(j + 1) * THREADS + tid];
        unsigned cods[4] = {cur.x, cur.y, cur.z, cur.w};
        #pragma unroll
        for (int s = 0; s < 4; ++s) {
            unsigned w = cods[s];
            float f = *(const float*)(qb + (w & 0xFFFFu))
                    * *(const float*)(qb + 16384u + (w >> 16));
            mymax = fmaxf(mymax, f);
        }
        if (j + 1 < ITERS) cur = nxt;
    }
    smax[tid] = mymax;
    __syncthreads();

    // --- phase 4: wave 0 extracts 8th-largest thread max -> threshold ---
    if (tid < 64) {
        float m[8];
        #pragma unroll
        for (int k = 0; k < 8; ++k) m[k] = smax[tid + 64 * k];
        float thr = -1.0f;
        #pragma unroll
        for (int round = 0; round < 8; ++round) {
            float lm = m[0];
            #pragma unroll
            for (int k = 1; k < 8; ++k) lm = fmaxf(lm, m[k]);
            float wm = lm;
            #pragma unroll
            for (int off = 32; off >= 1; off >>= 1)
                wm = fmaxf(wm, __shfl_xor(wm, off, 64));
            unsigned long long bal = __ballot(lm == wm);
            int first = (int)__ffsll(bal) - 1;
            if (tid == first) {                 // remove exactly one instance
                bool done = false;
                #pragma unroll
                for (int k = 0; k < 8; ++k) {
                    bool rm = (!done) && (m[k] == wm);
                    m[k] = rm ? -2.0f : m[k];
                    done = done || rm;
                }
            }
            thr = wm;
        }
        if (tid == 0) sthr = thr;
    }
    __syncthreads();

    // --- phase 5: threads whose max qualifies recompute & push candidates ---
    {
        const float thr = sthr;
        if (mymax >= thr) {                    // ~8-30 threads of 512
            for (int j = 0; j < ITERS; ++j) {
                uint4 cd = pk4[j * THREADS + tid];
                unsigned cods[4] = {cd.x, cd.y, cd.z, cd.w};
                #pragma unroll
                for (int s = 0; s < 4; ++s) {
                    unsigned w = cods[s];
                    float f = *(const float*)(qb + (w & 0xFFFFu))
                            * *(const float*)(qb + 16384u + (w >> 16));
                    if (f >= thr) {
                        int flat = (j * THREADS + tid) * 4 + s;
                        int oid  = SORTED ? g_sidx[flat] : flat;
                        int pos = atomicAdd(&scnt, 1);
                        if (pos < CAP) {
                            cvals[pos] = f;
                            cidx[pos]  = oid;
                        }
                    }
                }
            }
        }
    }
    __syncthreads();

    // --- phase 6: exact rank selection (val desc, original idx asc) ---
    if (tid < 64) {
        int n = scnt < CAP ? scnt : CAP;
        for (int c = tid; c < n; c += 64) {
            float v  = cvals[c];
            int   id = cidx[c];
            int r = 0;
            for (int mI = 0; mI < n; ++mI) {
                float vm = cvals[mI];
                int   im = cidx[mI];
                r += ((vm > v) || (vm == v && im < id)) ? 1 : 0;
            }
            if (r < 8) {
                wv[r] = v;
                wc[r] = consequents[id];
            }
        }
    }
    __syncthreads();

    // --- phase 7: defuzzify ---
    if (tid == 0) {
        float num = 0.0f, den = 0.0f;
        #pragma unroll
        for (int k = 0; k < 8; ++k) {
            num += wv[k] * s1s[wc[k]];
            den += wv[k] * s0s[wc[k]];
        }
        out[b] = num / (den + EPSF);
    }
}

// ---------------- generic fallback (round-1 kernel, inline pack) ------------
__global__ __launch_bounds__(256) void anfis_kernel(
    const float* __restrict__ x,
    const int* __restrict__ ant,
    const int* __restrict__ consequents,
    const float* __restrict__ in_centers,
    const float* __restrict__ in_widths,
    const float* __restrict__ out_centers,
    const float* __restrict__ out_widths,
    float* __restrict__ out,
    int R)
{
    __shared__ float mu[64];
    __shared__ float pairs[256];
    __shared__ float s0s[MOO], s1s[MOO];
    __shared__ float svals[256][9];
    __shared__ int   sidx[256][9];

    const int tid = threadIdx.x;
    const int b   = blockIdx.x;

    if (tid < 64) {
        int d = tid >> 3, c = tid & 7;
        float v = 1.0f;
        if (c < MM) {
            float z = (x[b * DD + d] - in_centers[d * MM + c]) / in_widths[d * MM + c];
            v = expf(-0.5f * z * z);
            v = fminf(v, 1.0f);
            v = fmaxf(v, EPSF);
        }
        mu[tid] = v;
    } else if (tid < 64 + MOO) {
        int mo = tid - 64;
        float oc = out_centers[mo], ow = out_widths[mo];
        float s0 = 0.0f, s1 = 0.0f;
        for (int p = 0; p < NPTS; ++p) {
            float u = (float)p * (1.0f / 99.0f);
            float z = (u - oc) / ow;
            float e = expf(-0.5f * z * z);
            s0 += e;
            s1 += u * e;
        }
        s0s[mo] = s0;
        s1s[mo] = s1;
    }
    __syncthreads();

    {
        int p = tid >> 6, q = tid & 63;
        pairs[tid] = mu[(2 * p) * 8 + (q & 7)] * mu[(2 * p + 1) * 8 + (q >> 3)];
    }
    __syncthreads();

    float vals[8];
    int   idxs[8];
    #pragma unroll
    for (int k = 0; k < 8; ++k) { vals[k] = -1.0f; idxs[k] = 0x7fffffff; }

    for (int r = tid; r < R; r += 256) {
        const int4* a = reinterpret_cast<const int4*>(ant) + (size_t)r * 2;
        int4 lo = a[0], hi = a[1];
        int v[8] = {lo.x, lo.y, lo.z, lo.w, hi.x, hi.y, hi.z, hi.w};
        unsigned code = 0u;
        #pragma unroll
        for (int i = 0; i < 8; ++i) {
            int c = v[i];
            c = (c < 0) ? 7 : (c > MM - 1 ? MM - 1 : c);
            code |= (unsigned)c << (3 * i);
        }
        float f = pairs[code & 63]
                * pairs[64  + ((code >> 6)  & 63)]
                * pairs[128 + ((code >> 12) & 63)]
                * pairs[192 + ((code >> 18) & 63)];
        if (f > vals[7]) {
            float nv = f; int ni = r;
            #pragma unroll
            for (int k = 0; k < 8; ++k) {
                bool take = nv > vals[k];
                float cv = vals[k]; int ci = idxs[k];
                vals[k] = take ? nv : cv;
                idxs[k] = take ? ni : ci;
                nv = take ? cv : nv;
                ni = take ? ci : ni;
            }
        }
    }

    #pragma unroll
    for (int k = 0; k < 8; ++k) { svals[tid][k] = vals[k]; sidx[tid][k] = idxs[k]; }

    for (int off = 128; off >= 1; off >>= 1) {
        __syncthreads();
        if (tid < off) {
            float ov[8]; int oi[8];
            int pa = 0, pb = 0;
            #pragma unroll
            for (int k = 0; k < 8; ++k) {
                float va = svals[tid][pa];        int ia = sidx[tid][pa];
                float vb = svals[tid + off][pb];  int ib = sidx[tid + off][pb];
                bool ta = (va > vb) || ((va == vb) && (ia < ib));
                ov[k] = ta ? va : vb;
                oi[k] = ta ? ia : ib;
                pa += ta ? 1 : 0;
                pb += ta ? 0 : 1;
            }
            #pragma unroll
            for (int k = 0; k < 8; ++k) { svals[tid][k] = ov[k]; sidx[tid][k] = oi[k]; }
        }
    }
    __syncthreads();

    if (tid == 0) {
        float num = 0.0f, den = 0.0f;
        #pragma unroll
        for (int k = 0; k < 8; ++k) {
            float v = svals[0][k];
            int   c = consequents[sidx[0][k]];
            num += v * s1s[c];
            den += v * s0s[c];
        }
        out[b] = num / (den + EPSF);
    }
}

extern "C" void kernel_launch(void* const* d_in, const int* in_sizes, int n_in,
                              void* d_out, int out_size, void* d_ws, size_t ws_size,
                              hipStream_t stream) {
    const float* x      = (const float*)d_in[0];
    const int*   ant    = (const int*)d_in[1];
    const int*   cons   = (const int*)d_in[2];
    const float* in_c   = (const float*)d_in[3];
    const float* in_w   = (const float*)d_in[4];
    const float* out_c  = (const float*)d_in[5];
    const float* out_w  = (const float*)d_in[6];
    float*       out    = (float*)d_out;

    const int B = in_sizes[0] / DD;
    const int R = in_sizes[1] / DD;

    const bool shape_ok = (R == THREADS * 4 * ITERS);          // R == 32768
    const size_t need_sorted = (size_t)R * 12;                 // off + soff + sidx
    const size_t need_plain  = (size_t)R * 4;

    if (shape_ok && d_ws && ws_size >= need_sorted) {
        unsigned* g_off  = (unsigned*)d_ws;
        unsigned* g_soff = g_off + R;
        int*      g_sidx = (int*)(g_soff + R);
        pack_kernel<<<(R + 255) / 256, 256, 0, stream>>>(ant, g_off, R);
        sort_kernel<<<1, 1024, 0, stream>>>(g_off, g_soff, g_sidx, R);
        anfis_fast<true><<<B, THREADS, 0, stream>>>(x, g_soff, g_sidx, cons,
                                                    in_c, in_w, out_c, out_w, out);
    } else if (shape_ok && d_ws && ws_size >= need_plain) {
        unsigned* g_off = (unsigned*)d_ws;
        pack_kernel<<<(R + 255) / 256, 256, 0, stream>>>(ant, g_off, R);
        anfis_fast<false><<<B, THREADS, 0, stream>>>(x, g_off, nullptr, cons,
                                                     in_c, in_w, out_c, out_w, out);
    } else {
        anfis_kernel<<<B, 256, 0, stream>>>(x, ant, cons, in_c, in_w,
                                            out_c, out_w, out, R);
    }
}

// Round 4
// 77.270 us; speedup vs baseline: 1.4085x; 1.4085x over previous
//
#include <hip/hip_runtime.h>
#include <math.h>

#define DD 8
#define MM 7
#define MOO 9
#define NPTS 100
#define EPSF 1e-5f

#define THREADS 512
#define ITERS 16          // THREADS*4*ITERS == 32768 rules
#define CAP 256           // candidate buffer capacity
#define NBUCK 4096        // hi-12-bit buckets

// ---------------- pack kernel: antecedents -> packed byte-offset word -------
// lo 16 bits: byte offset into quad table 0 (dims 0-3)
// hi 16 bits: byte offset (>>2 ... <<2 form) into quad table 1 (dims 4-7)
__global__ __launch_bounds__(256) void pack_kernel(const int* __restrict__ ant,
                                                   unsigned* __restrict__ g_off,
                                                   int R) {
    int r = blockIdx.x * 256 + threadIdx.x;
    if (r < R) {
        const int4* a = reinterpret_cast<const int4*>(ant) + (size_t)r * 2;
        int4 lo = a[0], hi = a[1];
        int v[8] = {lo.x, lo.y, lo.z, lo.w, hi.x, hi.y, hi.z, hi.w};
        unsigned code = 0u;
        #pragma unroll
        for (int i = 0; i < 8; ++i) {
            int c = v[i];
            c = (c < 0) ? 7 : (c > MM - 1 ? MM - 1 : c);   // -1 -> wildcard slot 7
            code |= (unsigned)c << (3 * i);
        }
        g_off[r] = ((code & 4095u) << 2) | ((code >> 12) << 18);
    }
}

// ---------------- hist+scan: one small block, writes all 4096 bucket bases --
// Rewrites every g_base entry each call -> no zeroing kernel, no stale state.
__global__ __launch_bounds__(1024) void hist_scan_kernel(const unsigned* __restrict__ g_off,
                                                         unsigned* __restrict__ g_base,
                                                         int R) {
    __shared__ unsigned hist[NBUCK];
    __shared__ unsigned aux[1024];
    const int tid = threadIdx.x;

    for (int i = tid; i < NBUCK; i += 1024) hist[i] = 0u;
    __syncthreads();

    for (int r = tid; r < R; r += 1024)
        atomicAdd(&hist[g_off[r] >> 18], 1u);
    __syncthreads();

    unsigned h0 = hist[4 * tid], h1 = hist[4 * tid + 1];
    unsigned h2 = hist[4 * tid + 2], h3 = hist[4 * tid + 3];
    aux[tid] = h0 + h1 + h2 + h3;
    __syncthreads();
    for (int off = 1; off < 1024; off <<= 1) {
        unsigned v = (tid >= off) ? aux[tid - off] : 0u;
        __syncthreads();
        aux[tid] += v;
        __syncthreads();
    }
    unsigned base = tid ? aux[tid - 1] : 0u;
    g_base[4 * tid]     = base;
    g_base[4 * tid + 1] = base + h0;
    g_base[4 * tid + 2] = base + h0 + h1;
    g_base[4 * tid + 3] = base + h0 + h1 + h2;
}

// ---------------- scatter: parallel bucket placement + wave permutation -----
// Rank q lands at p so that each main-kernel wave-instruction reads 64
// CONSECUTIVE sorted rules (hi-table -> ~8-word broadcast runs). Atomic order
// within a bucket is arbitrary -- harmless (final selection uses orig idx).
__global__ __launch_bounds__(256) void scatter_kernel(const unsigned* __restrict__ g_off,
                                                      unsigned* __restrict__ g_base,
                                                      unsigned* __restrict__ g_soff,
                                                      int* __restrict__ g_sidx,
                                                      int R) {
    int r = blockIdx.x * 256 + threadIdx.x;
    if (r < R) {
        unsigned w = g_off[r];
        unsigned q = atomicAdd(&g_base[w >> 18], 1u);
        unsigned p = (q & ~255u) | ((q & 63u) << 2) | ((q >> 6) & 3u);
        g_soff[p] = w;
        g_sidx[p] = r;
    }
}

// ---------------- fast kernel: one block (512 thr) per batch row ------------
template <bool SORTED>
__global__ __launch_bounds__(THREADS, 8) void anfis_fast(
    const float* __restrict__ x,
    const unsigned* __restrict__ stream_off,   // sorted (or raw) offset words
    const int* __restrict__ g_sidx,            // rank -> original rule (SORTED)
    const int* __restrict__ consequents,
    const float* __restrict__ in_centers,   // [D][M]
    const float* __restrict__ in_widths,    // [D][M]
    const float* __restrict__ out_centers,  // [MO]
    const float* __restrict__ out_widths,   // [MO]
    float* __restrict__ out)
{
    __shared__ float mu[64];          // [d][c], c==7 -> 1.0
    __shared__ float pairs[256];      // 4 x 64 pair products
    __shared__ float quads[8192];     // 2 x 4096 quad products (byte-indexed)
    __shared__ float s0s[MOO], s1s[MOO];
    __shared__ float smax[THREADS];
    __shared__ float sthr;
    __shared__ int   scnt;
    __shared__ float cvals[CAP];
    __shared__ int   cidx[CAP];
    __shared__ float wv[8];
    __shared__ int   wc[8];

    const int tid = threadIdx.x;
    const int b   = blockIdx.x;

    // --- phase 0: membership table + defuzz constants ---
    if (tid < 64) {
        int d = tid >> 3, c = tid & 7;
        float v = 1.0f;
        if (c < MM) {
            float z = (x[b * DD + d] - in_centers[d * MM + c]) / in_widths[d * MM + c];
            v = expf(-0.5f * z * z);
            v = fminf(v, 1.0f);
            v = fmaxf(v, EPSF);
        }
        mu[tid] = v;
    } else if (tid < 64 + MOO) {
        int mo = tid - 64;
        float oc = out_centers[mo], ow = out_widths[mo];
        float s0 = 0.0f, s1 = 0.0f;
        for (int p = 0; p < NPTS; ++p) {
            float u = (float)p * (1.0f / 99.0f);
            float z = (u - oc) / ow;
            float e = expf(-0.5f * z * z);
            s0 += e;
            s1 += u * e;
        }
        s0s[mo] = s0;
        s1s[mo] = s1;
    }
    __syncthreads();

    // --- phase 1: pair products (4 tables x 64) ---
    if (tid < 256) {
        int p = tid >> 6, q = tid & 63;
        pairs[tid] = mu[(2 * p) * 8 + (q & 7)] * mu[(2 * p + 1) * 8 + (q >> 3)];
    }
    __syncthreads();

    // --- phase 2: quad products (2 tables x 4096) ---
    #pragma unroll
    for (int k = tid; k < 8192; k += THREADS) {
        int t = k & 4095, hi = k >> 12;      // hi in {0,1}
        quads[k] = pairs[hi * 128 + (t & 63)] * pairs[hi * 128 + 64 + ((t >> 6) & 63)];
    }
    if (tid == 0) scnt = 0;
    __syncthreads();

    // --- phase 3: evaluate all rules, track per-thread max only ---
    const uint4* pk4 = reinterpret_cast<const uint4*>(stream_off);
    const char* qb = (const char*)quads;
    float mymax = -1.0f;
    uint4 cur = pk4[tid];
    #pragma unroll
    for (int j = 0; j < ITERS; ++j) {
        uint4 nxt;
        if (j + 1 < ITERS) nxt = pk4[(j + 1) * THREADS + tid];
        unsigned cods[4] = {cur.x, cur.y, cur.z, cur.w};
        #pragma unroll
        for (int s = 0; s < 4; ++s) {
            unsigned w = cods[s];
            float f = *(const float*)(qb + (w & 0xFFFFu))
                    * *(const float*)(qb + 16384u + (w >> 16));
            mymax = fmaxf(mymax, f);
        }
        if (j + 1 < ITERS) cur = nxt;
    }
    smax[tid] = mymax;
    __syncthreads();

    // --- phase 4: wave 0 extracts 8th-largest thread max -> threshold ---
    if (tid < 64) {
        float m[8];
        #pragma unroll
        for (int k = 0; k < 8; ++k) m[k] = smax[tid + 64 * k];
        float thr = -1.0f;
        #pragma unroll
        for (int round = 0; round < 8; ++round) {
            float lm = m[0];
            #pragma unroll
            for (int k = 1; k < 8; ++k) lm = fmaxf(lm, m[k]);
            float wm = lm;
            #pragma unroll
            for (int off = 32; off >= 1; off >>= 1)
                wm = fmaxf(wm, __shfl_xor(wm, off, 64));
            unsigned long long bal = __ballot(lm == wm);
            int first = (int)__ffsll(bal) - 1;
            if (tid == first) {                 // remove exactly one instance
                bool done = false;
                #pragma unroll
                for (int k = 0; k < 8; ++k) {
                    bool rm = (!done) && (m[k] == wm);
                    m[k] = rm ? -2.0f : m[k];
                    done = done || rm;
                }
            }
            thr = wm;
        }
        if (tid == 0) sthr = thr;
    }
    __syncthreads();

    // --- phase 5: threads whose max qualifies recompute & push candidates ---
    {
        const float thr = sthr;
        if (mymax >= thr) {                    // ~8-30 threads of 512
            for (int j = 0; j < ITERS; ++j) {
                uint4 cd = pk4[j * THREADS + tid];
                unsigned cods[4] = {cd.x, cd.y, cd.z, cd.w};
                #pragma unroll
                for (int s = 0; s < 4; ++s) {
                    unsigned w = cods[s];
                    float f = *(const float*)(qb + (w & 0xFFFFu))
                            * *(const float*)(qb + 16384u + (w >> 16));
                    if (f >= thr) {
                        int flat = (j * THREADS + tid) * 4 + s;
                        int oid  = SORTED ? g_sidx[flat] : flat;
                        int pos = atomicAdd(&scnt, 1);
                        if (pos < CAP) {
                            cvals[pos] = f;
                            cidx[pos]  = oid;
                        }
                    }
                }
            }
        }
    }
    __syncthreads();

    // --- phase 6: exact rank selection (val desc, original idx asc) ---
    if (tid < 64) {
        int n = scnt < CAP ? scnt : CAP;
        for (int c = tid; c < n; c += 64) {
            float v  = cvals[c];
            int   id = cidx[c];
            int r = 0;
            for (int mI = 0; mI < n; ++mI) {
                float vm = cvals[mI];
                int   im = cidx[mI];
                r += ((vm > v) || (vm == v && im < id)) ? 1 : 0;
            }
            if (r < 8) {
                wv[r] = v;
                wc[r] = consequents[id];
            }
        }
    }
    __syncthreads();

    // --- phase 7: defuzzify ---
    if (tid == 0) {
        float num = 0.0f, den = 0.0f;
        #pragma unroll
        for (int k = 0; k < 8; ++k) {
            num += wv[k] * s1s[wc[k]];
            den += wv[k] * s0s[wc[k]];
        }
        out[b] = num / (den + EPSF);
    }
}

// ---------------- generic fallback (round-1 kernel, inline pack) ------------
__global__ __launch_bounds__(256) void anfis_kernel(
    const float* __restrict__ x,
    const int* __restrict__ ant,
    const int* __restrict__ consequents,
    const float* __restrict__ in_centers,
    const float* __restrict__ in_widths,
    const float* __restrict__ out_centers,
    const float* __restrict__ out_widths,
    float* __restrict__ out,
    int R)
{
    __shared__ float mu[64];
    __shared__ float pairs[256];
    __shared__ float s0s[MOO], s1s[MOO];
    __shared__ float svals[256][9];
    __shared__ int   sidx[256][9];

    const int tid = threadIdx.x;
    const int b   = blockIdx.x;

    if (tid < 64) {
        int d = tid >> 3, c = tid & 7;
        float v = 1.0f;
        if (c < MM) {
            float z = (x[b * DD + d] - in_centers[d * MM + c]) / in_widths[d * MM + c];
            v = expf(-0.5f * z * z);
            v = fminf(v, 1.0f);
            v = fmaxf(v, EPSF);
        }
        mu[tid] = v;
    } else if (tid < 64 + MOO) {
        int mo = tid - 64;
        float oc = out_centers[mo], ow = out_widths[mo];
        float s0 = 0.0f, s1 = 0.0f;
        for (int p = 0; p < NPTS; ++p) {
            float u = (float)p * (1.0f / 99.0f);
            float z = (u - oc) / ow;
            float e = expf(-0.5f * z * z);
            s0 += e;
            s1 += u * e;
        }
        s0s[mo] = s0;
        s1s[mo] = s1;
    }
    __syncthreads();

    {
        int p = tid >> 6, q = tid & 63;
        pairs[tid] = mu[(2 * p) * 8 + (q & 7)] * mu[(2 * p + 1) * 8 + (q >> 3)];
    }
    __syncthreads();

    float vals[8];
    int   idxs[8];
    #pragma unroll
    for (int k = 0; k < 8; ++k) { vals[k] = -1.0f; idxs[k] = 0x7fffffff; }

    for (int r = tid; r < R; r += 256) {
        const int4* a = reinterpret_cast<const int4*>(ant) + (size_t)r * 2;
        int4 lo = a[0], hi = a[1];
        int v[8] = {lo.x, lo.y, lo.z, lo.w, hi.x, hi.y, hi.z, hi.w};
        unsigned code = 0u;
        #pragma unroll
        for (int i = 0; i < 8; ++i) {
            int c = v[i];
            c = (c < 0) ? 7 : (c > MM - 1 ? MM - 1 : c);
            code |= (unsigned)c << (3 * i);
        }
        float f = pairs[code & 63]
                * pairs[64  + ((code >> 6)  & 63)]
                * pairs[128 + ((code >> 12) & 63)]
                * pairs[192 + ((code >> 18) & 63)];
        if (f > vals[7]) {
            float nv = f; int ni = r;
            #pragma unroll
            for (int k = 0; k < 8; ++k) {
                bool take = nv > vals[k];
                float cv = vals[k]; int ci = idxs[k];
                vals[k] = take ? nv : cv;
                idxs[k] = take ? ni : ci;
                nv = take ? cv : nv;
                ni = take ? ci : ni;
            }
        }
    }

    #pragma unroll
    for (int k = 0; k < 8; ++k) { svals[tid][k] = vals[k]; sidx[tid][k] = idxs[k]; }

    for (int off = 128; off >= 1; off >>= 1) {
        __syncthreads();
        if (tid < off) {
            float ov[8]; int oi[8];
            int pa = 0, pb = 0;
            #pragma unroll
            for (int k = 0; k < 8; ++k) {
                float va = svals[tid][pa];        int ia = sidx[tid][pa];
                float vb = svals[tid + off][pb];  int ib = sidx[tid + off][pb];
                bool ta = (va > vb) || ((va == vb) && (ia < ib));
                ov[k] = ta ? va : vb;
                oi[k] = ta ? ia : ib;
                pa += ta ? 1 : 0;
                pb += ta ? 0 : 1;
            }
            #pragma unroll
            for (int k = 0; k < 8; ++k) { svals[tid][k] = ov[k]; sidx[tid][k] = oi[k]; }
        }
    }
    __syncthreads();

    if (tid == 0) {
        float num = 0.0f, den = 0.0f;
        #pragma unroll
        for (int k = 0; k < 8; ++k) {
            float v = svals[0][k];
            int   c = consequents[sidx[0][k]];
            num += v * s1s[c];
            den += v * s0s[c];
        }
        out[b] = num / (den + EPSF);
    }
}

extern "C" void kernel_launch(void* const* d_in, const int* in_sizes, int n_in,
                              void* d_out, int out_size, void* d_ws, size_t ws_size,
                              hipStream_t stream) {
    const float* x      = (const float*)d_in[0];
    const int*   ant    = (const int*)d_in[1];
    const int*   cons   = (const int*)d_in[2];
    const float* in_c   = (const float*)d_in[3];
    const float* in_w   = (const float*)d_in[4];
    const float* out_c  = (const float*)d_in[5];
    const float* out_w  = (const float*)d_in[6];
    float*       out    = (float*)d_out;

    const int B = in_sizes[0] / DD;
    const int R = in_sizes[1] / DD;

    const bool shape_ok = (R == THREADS * 4 * ITERS);                  // R == 32768
    const size_t need_sorted = (size_t)R * 12 + (size_t)NBUCK * 4;     // off+soff+sidx+bases
    const size_t need_plain  = (size_t)R * 4;

    if (shape_ok && d_ws && ws_size >= need_sorted) {
        unsigned* g_off  = (unsigned*)d_ws;
        unsigned* g_soff = g_off + R;
        int*      g_sidx = (int*)(g_soff + R);
        unsigned* g_base = (unsigned*)(g_sidx + R);
        pack_kernel<<<(R + 255) / 256, 256, 0, stream>>>(ant, g_off, R);
        hist_scan_kernel<<<1, 1024, 0, stream>>>(g_off, g_base, R);
        scatter_kernel<<<(R + 255) / 256, 256, 0, stream>>>(g_off, g_base, g_soff, g_sidx, R);
        anfis_fast<true><<<B, THREADS, 0, stream>>>(x, g_soff, g_sidx, cons,
                                                    in_c, in_w, out_c, out_w, out);
    } else if (shape_ok && d_ws && ws_size >= need_plain) {
        unsigned* g_off = (unsigned*)d_ws;
        pack_kernel<<<(R + 255) / 256, 256, 0, stream>>>(ant, g_off, R);
        anfis_fast<false><<<B, THREADS, 0, stream>>>(x, g_off, nullptr, cons,
                                                     in_c, in_w, out_c, out_w, out);
    } else {
        anfis_kernel<<<B, 256, 0, stream>>>(x, ant, cons, in_c, in_w,
                                            out_c, out_w, out, R);
    }
}